// Round 11
// baseline (318.451 us; speedup 1.0000x reference)
//
#include <hip/hip_runtime.h>
#include <hip/hip_fp16.h>
#include <math.h>

// 2-layer GAT. f16 MFMA GEMMs (fused attention-scalar B-tiles, fused fp32->f16
// A-convert), fp8-e4m3 feature storage for the edge gathers, single-pass
// segment softmax, fp32 accumulation.
//
// CSR build (R17, validated R6): ATOMIC-FREE multi-split; split fused with
// gemm1. Zero device atomics.
//
// Aggregation: R3 8-stage pipeline bodies (validated best: 63.9us, VGPR 28,
// 2.80 TB/s). FUSION LEDGER: R16 diet regressed; R19 barrier-coupled fusion
// = degree-tail 1.45x; R20 coupling-free fusion = VGPR-union occupancy
// collapse. agg1 lives alone, single dispatch.
//
// R22: k_final gather fix. Old: one THREAD per segment, ~10 serial 4-B reads,
// 64 lanes hitting 64 segments ~16KB apart -> every read its own 64-B line
// (~16x overfetch, ~102MB, latency-bound). New: one WAVE per segment, lanes
// 0..cnt-1 load consecutive ints in one instruction (1-2 lines/segment,
// ~12MB). R21's diagnostic (fused1 52us idle; >=120us hidden in final/agg2)
// motivated this; top-5 this round finally shows final+agg2 counters.

typedef _Float16 f16x8 __attribute__((ext_vector_type(8)));   // 8 f16 (4 VGPRs)
typedef float f32x4 __attribute__((ext_vector_type(4)));
typedef float f32x2 __attribute__((ext_vector_type(2)));

__device__ __forceinline__ float lrelu02(float x){ return x > 0.f ? x : 0.2f*x; }
__device__ __forceinline__ unsigned char f2fp8(float v){
  return (unsigned char)(__builtin_amdgcn_cvt_pk_fp8_f32(v, v, 0, false) & 0xff);
}

#define BSHIFT 8                 // 256 nodes per bucket
#define BMASK  255
#define SPLIT_CHUNK 4096         // edges per split block (= private tmp region)

// ---------------- split body: block-private bucket sort (NO device atomics) ----------------
__device__ __forceinline__ void split_body(int blk, const int* __restrict__ src,
    const int* __restrict__ dst, int* __restrict__ hp, int* __restrict__ tmp,
    int E, int nb1){
  __shared__ int hist[512];
  __shared__ int hoff[512];
  __shared__ int sb[256];
  int tid = threadIdx.x;
  #pragma unroll
  for (int t = tid; t < 512; t += 256) hist[t] = 0;
  __syncthreads();
  int lo = blk*SPLIT_CHUNK;
  int ds[16], ss[16];
  #pragma unroll
  for (int k = 0; k < 16; ++k){
    int i = lo + tid + k*256;
    bool p = i < E;
    ds[k] = p ? dst[i] : 0;
    ss[k] = p ? src[i] : 0;
    if (p) atomicAdd(&hist[ds[k] >> BSHIFT], 1);     // LDS atomic
  }
  __syncthreads();
  int v0 = hist[2*tid], v1 = hist[2*tid+1];
  sb[tid] = v0 + v1;
  __syncthreads();
  for (int off = 1; off < 256; off <<= 1){
    int x = (tid >= off) ? sb[tid-off] : 0;
    __syncthreads();
    sb[tid] += x;
    __syncthreads();
  }
  int base = (tid == 0) ? 0 : sb[tid-1];
  hoff[2*tid]   = base;
  hoff[2*tid+1] = base + v0;
  __syncthreads();
  for (int b = tid; b < nb1; b += 256) hp[blk*nb1 + b] = hoff[b];
  __syncthreads();
  #pragma unroll
  for (int k = 0; k < 16; ++k){
    int i = lo + tid + k*256;
    if (i < E){
      int r = atomicAdd(&hoff[ds[k] >> BSHIFT], 1);  // LDS atomic, private region pos
      tmp[blk*SPLIT_CHUNK + r] = ss[k] | ((ds[k] & BMASK) << 17);
    }
  }
}

// ---------------- GEMM1 body (MFMA f16): h1 (fp8) + a1i/a1j ----------------
__device__ __forceinline__ void gemm1_body(int gb, const float* __restrict__ x,
    const _Float16* __restrict__ Wh, const _Float16* __restrict__ attB,
    const float* __restrict__ b1, const float* __restrict__ consts,
    unsigned char* __restrict__ h1f8, float* __restrict__ a1i, float* __restrict__ a1j, int N){
  int wid  = (gb*256 + (int)threadIdx.x) >> 6;
  int lane = threadIdx.x & 63;
  int m0 = wid*16;
  if (m0 >= N) return;
  int col = lane & 15, quad = lane >> 4;
  const float* xr = x + (size_t)(m0+col)*128 + quad*8;
  f32x4 acc[9];
  #pragma unroll
  for (int t=0;t<9;t++){ acc[t][0]=0.f; acc[t][1]=0.f; acc[t][2]=0.f; acc[t][3]=0.f; }
  #pragma unroll
  for (int q=0;q<4;q++){
    float4 f0 = ((const float4*)(xr + q*32))[0];
    float4 f1 = ((const float4*)(xr + q*32))[1];
    f16x8 a;
    a[0]=(_Float16)f0.x; a[1]=(_Float16)f0.y; a[2]=(_Float16)f0.z; a[3]=(_Float16)f0.w;
    a[4]=(_Float16)f1.x; a[5]=(_Float16)f1.y; a[6]=(_Float16)f1.z; a[7]=(_Float16)f1.w;
    #pragma unroll
    for (int t=0;t<8;t++){
      const f16x8* Bp = (const f16x8*)(Wh + (size_t)(t*16+col)*128 + q*32 + quad*8);
      acc[t] = __builtin_amdgcn_mfma_f32_16x16x32_f16(a, *Bp, acc[t], 0,0,0);
    }
    const f16x8* Ap = (const f16x8*)(attB + (size_t)col*128 + q*32 + quad*8);
    acc[8] = __builtin_amdgcn_mfma_f32_16x16x32_f16(a, *Ap, acc[8], 0,0,0);
  }
  #pragma unroll
  for (int t=0;t<8;t++){
    int c = t*16 + col;
    float bb = b1[c];
    #pragma unroll
    for (int r=0;r<4;r++){
      h1f8[(size_t)(m0 + quad*4 + r)*128 + c] = f2fp8(acc[t][r] + bb);
    }
  }
  float hb = consts[col];
  #pragma unroll
  for (int r=0;r<4;r++){
    int node = m0 + quad*4 + r;
    float v = acc[8][r] + hb;
    if (col < 8) a1i[node*8 + col] = v;
    else         a1j[node*8 + (col-8)] = v;
  }
}

// ---------------- fused: split (independent) || gemm1 ----------------
__global__ __launch_bounds__(256) void k_fused1(const int* __restrict__ src,
    const int* __restrict__ dst, int* __restrict__ hp, int* __restrict__ tmp,
    int E, int nb1, int nchunk,
    const float* __restrict__ x, const _Float16* __restrict__ Wh,
    const _Float16* __restrict__ attB, const float* __restrict__ b1,
    const float* __restrict__ consts, unsigned char* __restrict__ h1f8,
    float* __restrict__ a1i, float* __restrict__ a1j, int N){
  if ((int)blockIdx.x < nchunk)
    split_body(blockIdx.x, src, dst, hp, tmp, E, nb1);
  else
    gemm1_body(blockIdx.x - nchunk, x, Wh, attB, b1, consts, h1f8, a1i, a1j, N);
}

// ---------------- column sums: tot[b] = sum_blk cnt[blk][b] ----------------
__global__ __launch_bounds__(256) void k_colsum(const int* __restrict__ hp,
    int* __restrict__ tot, int nchunk, int nb1){
  __shared__ int red[256];
  int b = blockIdx.x;
  int t = threadIdx.x;
  int s = 0;
  for (int blk = t; blk < nchunk; blk += 256)
    s += hp[blk*nb1 + b + 1] - hp[blk*nb1 + b];
  red[t] = s;
  __syncthreads();
  for (int off = 128; off > 0; off >>= 1){
    if (t < off) red[t] += red[t+off];
    __syncthreads();
  }
  if (t == 0) tot[b] = red[0];
}

// ---------------- bucket scan: tot -> bstart (exclusive) ----------------
__global__ void k_bscan(const int* __restrict__ tot, int* __restrict__ bstart,
                        int* __restrict__ rowstart, int nbucket, int E, int N){
  __shared__ int lds[256];
  int t = threadIdx.x;
  int v[4]; int s = 0;
  #pragma unroll
  for (int k = 0; k < 4; ++k){
    int idx = t*4 + k;
    v[k] = (idx < nbucket) ? tot[idx] : 0;
    s += v[k];
  }
  lds[t] = s;
  __syncthreads();
  for (int off = 1; off < 256; off <<= 1){
    int x = (t >= off) ? lds[t-off] : 0;
    __syncthreads();
    lds[t] += x;
    __syncthreads();
  }
  int run = (t == 0) ? 0 : lds[t-1];
  #pragma unroll
  for (int k = 0; k < 4; ++k){
    int idx = t*4 + k;
    if (idx < nbucket) bstart[idx] = run;
    run += v[k];
  }
  if (t == 0){ bstart[nbucket] = E; rowstart[N] = E; }
}

// ---------------- finalize: gather per-block segments -> node sort -> csr ----------------
#define STAGE_CAP 6144   // bucket mean 4096, sd ~64 -> mean+32sd headroom
__global__ __launch_bounds__(256) void k_final(const int* __restrict__ tmp,
    const int* __restrict__ hp, const int* __restrict__ bstart,
    int* __restrict__ rowstart, int* __restrict__ csr, int nchunk, int nb1, int N){
  __shared__ int stage[STAGE_CAP];
  __shared__ int c0[512];
  __shared__ int cv[512];
  __shared__ int ce[512];
  __shared__ int sb[256];
  __shared__ int h[256];
  __shared__ int sc[256];
  __shared__ int cur[256];
  int b = blockIdx.x;
  int tid = threadIdx.x;
  int base = bstart[b];
  int tot  = bstart[b+1] - base;
  #pragma unroll
  for (int t = tid; t < 512; t += 256){ c0[t] = 0; cv[t] = 0; }
  __syncthreads();
  for (int blk = tid; blk < nchunk; blk += 256){
    int o0 = hp[blk*nb1 + b];
    int o1 = hp[blk*nb1 + b + 1];
    c0[blk] = o0;
    cv[blk] = o1 - o0;
  }
  __syncthreads();
  int v0 = cv[2*tid], v1 = cv[2*tid+1];
  sb[tid] = v0 + v1;
  __syncthreads();
  for (int off = 1; off < 256; off <<= 1){
    int x = (tid >= off) ? sb[tid-off] : 0;
    __syncthreads();
    sb[tid] += x;
    __syncthreads();
  }
  int pbase = (tid == 0) ? 0 : sb[tid-1];
  ce[2*tid]   = pbase;
  ce[2*tid+1] = pbase + v0;
  __syncthreads();
  // gather segments into LDS stage: ONE WAVE PER SEGMENT (R22 fix).
  // Old per-thread-serial gather hit one 64-B line per 4-B read (~16x
  // overfetch). Lanes 0..cnt-1 now load consecutive ints in one instr.
  {
    int wv = tid >> 6, ln = tid & 63;
    for (int blk = wv; blk < nchunk; blk += 4){
      int cnt = cv[blk];
      int out = ce[blk];
      const int* tb = tmp + blk*SPLIT_CHUNK + c0[blk];
      for (int j = ln; j < cnt; j += 64){
        int o = out + j;
        if (o < STAGE_CAP) stage[o] = tb[j];
      }
    }
  }
  if (tid < 256) h[tid] = 0;
  __syncthreads();
  if (tot > STAGE_CAP) tot = STAGE_CAP;
  for (int i = tid; i < tot; i += 256) atomicAdd(&h[stage[i] >> 17], 1);
  __syncthreads();
  sc[tid] = h[tid];
  __syncthreads();
  for (int off = 1; off < 256; off <<= 1){
    int x = (tid >= off) ? sc[tid-off] : 0;
    __syncthreads();
    sc[tid] += x;
    __syncthreads();
  }
  {
    int excl = sc[tid] - h[tid];
    int node = b*256 + tid;
    if (node < N) rowstart[node] = base + excl;
    cur[tid] = excl;
  }
  __syncthreads();
  for (int i = tid; i < tot; i += 256){
    int v = stage[i];
    int p = atomicAdd(&cur[v >> 17], 1);
    csr[base + p] = v & 0x1FFFF;
  }
}

// ---------------- weight prep: f16 weights + att-folded tiles + bias consts ----------------
__global__ void k_prep(const float* __restrict__ W1, const float* __restrict__ b1,
                       const float* __restrict__ att1,
                       const float* __restrict__ W2, const float* __restrict__ b2,
                       const float* __restrict__ att2,
                       _Float16* __restrict__ W1h, _Float16* __restrict__ W2h,
                       _Float16* __restrict__ attB1, _Float16* __restrict__ attB2,
                       float* __restrict__ consts){
  int i = blockIdx.x*blockDim.x + threadIdx.x;
  if (i < 16384){ W1h[i] = (_Float16)W1[i]; return; }
  i -= 16384;
  if (i < 6144){ int r = i >> 7; W2h[i] = (r < 40)? (_Float16)W2[i] : (_Float16)0.f; return; }
  i -= 6144;
  if (i < 2048){
    int j = i >> 7, k = i & 127;
    int h = j & 7, half = (j >> 3)*16;
    float s = 0.f;
    for (int c = 0; c < 16; ++c) s += att1[h*32 + half + c]*W1[(h*16+c)*128 + k];
    attB1[i] = (_Float16)s; return;
  }
  i -= 2048;
  if (i < 2048){
    int j = i >> 7, k = i & 127;
    float s = 0.f;
    if (j < 2){ const float* av = att2 + j*40; for (int c = 0; c < 40; ++c) s += av[c]*W2[c*128 + k]; }
    attB2[i] = (_Float16)s; return;
  }
  i -= 2048;
  if (i < 18){
    float s = 0.f;
    if (i < 8){ for (int c = 0; c < 16; ++c) s += b1[i*16+c]*att1[i*32+c]; }
    else if (i < 16){ int h = i-8; for (int c = 0; c < 16; ++c) s += b1[h*16+c]*att1[h*32+16+c]; }
    else if (i == 16){ for (int c = 0; c < 40; ++c) s += b2[c]*att2[c]; }
    else { for (int c = 0; c < 40; ++c) s += b2[c]*att2[40+c]; }
    consts[i] = s;
  }
}

// ---------------- layer-1 agg body (EXACT R3, 63.9us validated) ----------------
__device__ __forceinline__ void agg1_node(int n, const uint2* __restrict__ h1q,
    const float* __restrict__ a1i, const float* __restrict__ a1j,
    const int* __restrict__ rowstart, const int* __restrict__ csr,
    const float* __restrict__ bias, uint4* __restrict__ x2u4, int N){
  if (n >= N) return;
  int lane = threadIdx.x & 63;
  int ql = lane & 15, qt = lane >> 4;
  unsigned hd = (unsigned)ql >> 1;
  int rs = rowstart[n], re = rowstart[n+1];
  float ai2 = a1i[(unsigned)n*8u + hd];
  float a0=0.f,a1=0.f,a2=0.f,a3=0.f,a4=0.f,a5=0.f,a6=0.f,a7=0.f,den=0.f;
  {
    float w = (qt==0)? __expf(lrelu02(ai2 + a1j[(unsigned)n*8u + hd])) : 0.f;
    uint2 u = h1q[(unsigned)n*16u + (unsigned)ql];
    f32x2 f0 = __builtin_amdgcn_cvt_pk_f32_fp8((int)u.x, false);
    f32x2 f1 = __builtin_amdgcn_cvt_pk_f32_fp8((int)u.x, true);
    f32x2 f2 = __builtin_amdgcn_cvt_pk_f32_fp8((int)u.y, false);
    f32x2 f3 = __builtin_amdgcn_cvt_pk_f32_fp8((int)u.y, true);
    a0=w*f0[0]; a1=w*f0[1]; a2=w*f1[0]; a3=w*f1[1];
    a4=w*f2[0]; a5=w*f2[1]; a6=w*f3[0]; a7=w*f3[1];
    den = w;
  }
  int last = re - 1;
  if (rs < re){
    unsigned cs0 = (unsigned)csr[min(rs+ 0+qt,last)];
    unsigned cs1 = (unsigned)csr[min(rs+ 4+qt,last)];
    unsigned cs2 = (unsigned)csr[min(rs+ 8+qt,last)];
    unsigned cs3 = (unsigned)csr[min(rs+12+qt,last)];
    unsigned cs4 = (unsigned)csr[min(rs+16+qt,last)];
    unsigned cs5 = (unsigned)csr[min(rs+20+qt,last)];
    unsigned cs6 = (unsigned)csr[min(rs+24+qt,last)];
    unsigned cs7 = (unsigned)csr[min(rs+28+qt,last)];
    float aj0 = a1j[cs0*8u+hd], aj1 = a1j[cs1*8u+hd];
    float aj2 = a1j[cs2*8u+hd], aj3 = a1j[cs3*8u+hd];
    float aj4 = a1j[cs4*8u+hd], aj5 = a1j[cs5*8u+hd];
    float aj6 = a1j[cs6*8u+hd], aj7 = a1j[cs7*8u+hd];
    uint2 u0 = h1q[(size_t)cs0*16u + (unsigned)ql];
    uint2 u1 = h1q[(size_t)cs1*16u + (unsigned)ql];
    uint2 u2 = h1q[(size_t)cs2*16u + (unsigned)ql];
    uint2 u3 = h1q[(size_t)cs3*16u + (unsigned)ql];
    int e0 = rs;

#define AGG1_ST(US, CF, CS, AJ, OFF)                                         \
    {                                                                        \
      uint2 cur = US;                                                        \
      US = h1q[(size_t)CF*16u + (unsigned)ql];                               \
      unsigned nc = (unsigned)csr[min(e0+OFF+32+qt, last)];                  \
      float w = (e0+OFF+qt < re)? __expf(lrelu02(ai2 + AJ)) : 0.f;           \
      den += w;                                                              \
      f32x2 g0 = __builtin_amdgcn_cvt_pk_f32_fp8((int)cur.x, false);         \
      f32x2 g1 = __builtin_amdgcn_cvt_pk_f32_fp8((int)cur.x, true);          \
      f32x2 g2 = __builtin_amdgcn_cvt_pk_f32_fp8((int)cur.y, false);         \
      f32x2 g3 = __builtin_amdgcn_cvt_pk_f32_fp8((int)cur.y, true);          \
      a0 += w*g0[0]; a1 += w*g0[1]; a2 += w*g1[0]; a3 += w*g1[1];            \
      a4 += w*g2[0]; a5 += w*g2[1]; a6 += w*g3[0]; a7 += w*g3[1];            \
      CS = nc; AJ = a1j[nc*8u + hd];                                         \
    }

    while (e0 < re){
      AGG1_ST(u0, cs4, cs0, aj0, 0)
      if (e0+4 >= re) break;
      AGG1_ST(u1, cs5, cs1, aj1, 4)
      if (e0+8 >= re) break;
      AGG1_ST(u2, cs6, cs2, aj2, 8)
      if (e0+12 >= re) break;
      AGG1_ST(u3, cs7, cs3, aj3, 12)
      if (e0+16 >= re) break;
      AGG1_ST(u0, cs0, cs4, aj4, 16)
      if (e0+20 >= re) break;
      AGG1_ST(u1, cs1, cs5, aj5, 20)
      if (e0+24 >= re) break;
      AGG1_ST(u2, cs2, cs6, aj6, 24)
      if (e0+28 >= re) break;
      AGG1_ST(u3, cs3, cs7, aj7, 28)
      e0 += 32;
    }
#undef AGG1_ST
  }
  #pragma unroll
  for (int off = 16; off < 64; off <<= 1){
    den += __shfl_xor(den, off);
    a0 += __shfl_xor(a0, off); a1 += __shfl_xor(a1, off);
    a2 += __shfl_xor(a2, off); a3 += __shfl_xor(a3, off);
    a4 += __shfl_xor(a4, off); a5 += __shfl_xor(a5, off);
    a6 += __shfl_xor(a6, off); a7 += __shfl_xor(a7, off);
  }
  if (qt == 0){
    float invd = 1.f/(den + 1e-16f);
    const float4* b4 = (const float4*)(bias + 8*ql);
    float4 bl = b4[0], bh = b4[1];
    float o0=a0*invd+bl.x, o1=a1*invd+bl.y, o2=a2*invd+bl.z, o3=a3*invd+bl.w;
    float o4=a4*invd+bh.x, o5=a5*invd+bh.y, o6=a6*invd+bh.z, o7=a7*invd+bh.w;
    o0=(o0>0.f)?o0:(__expf(o0)-1.f); o1=(o1>0.f)?o1:(__expf(o1)-1.f);
    o2=(o2>0.f)?o2:(__expf(o2)-1.f); o3=(o3>0.f)?o3:(__expf(o3)-1.f);
    o4=(o4>0.f)?o4:(__expf(o4)-1.f); o5=(o5>0.f)?o5:(__expf(o5)-1.f);
    o6=(o6>0.f)?o6:(__expf(o6)-1.f); o7=(o7>0.f)?o7:(__expf(o7)-1.f);
    __half2 p0 = __floats2half2_rn(o0,o1), p1 = __floats2half2_rn(o2,o3);
    __half2 p2 = __floats2half2_rn(o4,o5), p3 = __floats2half2_rn(o6,o7);
    uint4 o;
    o.x = *(unsigned*)&p0; o.y = *(unsigned*)&p1; o.z = *(unsigned*)&p2; o.w = *(unsigned*)&p3;
    x2u4[(unsigned)n*16u + (unsigned)ql] = o;
  }
}

// ---------------- agg1: one wave per node ----------------
__global__ __launch_bounds__(256) void k_agg1(const uint2* __restrict__ h1q,
    const float* __restrict__ a1i, const float* __restrict__ a1j,
    const int* __restrict__ rowstart, const int* __restrict__ csr,
    const float* __restrict__ bias, uint4* __restrict__ x2u4, int N){
  int n = (blockIdx.x*256 + (int)threadIdx.x) >> 6;
  agg1_node(n, h1q, a1i, a1j, rowstart, csr, bias, x2u4, N);
}

// ---------------- GEMM2 (MFMA f16): h2 (fp8) + a2i/a2j ----------------
__global__ __launch_bounds__(256) void k_gemm2(const _Float16* __restrict__ xh,
    const _Float16* __restrict__ Wh, const _Float16* __restrict__ attB,
    const float* __restrict__ b2, const float* __restrict__ consts,
    unsigned char* __restrict__ h2f8, float* __restrict__ a2i, float* __restrict__ a2j, int N){
  int wid  = (blockIdx.x*256 + threadIdx.x) >> 6;
  int lane = threadIdx.x & 63;
  int m0 = wid*16;
  if (m0 >= N) return;
  int col = lane & 15, quad = lane >> 4;
  const f16x8* A8 = (const f16x8*)(xh + (size_t)(m0+col)*128 + quad*8);
  f32x4 acc[4];
  #pragma unroll
  for (int t=0;t<4;t++){ acc[t][0]=0.f; acc[t][1]=0.f; acc[t][2]=0.f; acc[t][3]=0.f; }
  #pragma unroll
  for (int q=0;q<4;q++){
    f16x8 a = A8[q*4];
    #pragma unroll
    for (int t=0;t<3;t++){
      const f16x8* Bp = (const f16x8*)(Wh + (size_t)(t*16+col)*128 + q*32 + quad*8);
      acc[t] = __builtin_amdgcn_mfma_f32_16x16x32_f16(a, *Bp, acc[t], 0,0,0);
    }
    const f16x8* Bp2 = (const f16x8*)(attB + (size_t)col*128 + q*32 + quad*8);
    acc[3] = __builtin_amdgcn_mfma_f32_16x16x32_f16(a, *Bp2, acc[3], 0,0,0);
  }
  #pragma unroll
  for (int t=0;t<3;t++){
    int c = t*16 + col;
    if (c < 40){
      float bb = b2[c];
      #pragma unroll
      for (int r=0;r<4;r++){
        h2f8[(size_t)(m0 + quad*4 + r)*40 + c] = f2fp8(acc[t][r] + bb);
      }
    }
  }
  if (col < 2){
    float cc = consts[16 + col];
    #pragma unroll
    for (int r=0;r<4;r++){
      int node = m0 + quad*4 + r;
      if (col == 0) a2i[node] = acc[3][r] + cc;
      else          a2j[node] = acc[3][r] + cc;
    }
  }
}

// ---------------- layer-2 fused softmax+aggregate + log_softmax (EXACT R3) ----------------
__global__ __launch_bounds__(256) void k_agg2(const unsigned* __restrict__ h2u,
    const float* __restrict__ a2i, const float* __restrict__ a2j,
    const int* __restrict__ rowstart, const int* __restrict__ csr,
    const float* __restrict__ bias, float* __restrict__ out, int N){
  int lane = threadIdx.x & 63;
  int wid = (blockIdx.x*blockDim.x + threadIdx.x) >> 6;
  int qt = lane >> 4, ql = lane & 15;
  int n = wid*4 + qt;
  if (n >= N) return;
  bool act = ql < 10;
  unsigned cl = act ? (unsigned)ql : 0u;
  int rs = rowstart[n], re = rowstart[n+1];
  float ai = a2i[n];
  float wself = __expf(lrelu02(ai + a2j[n]));
  float a0,a1,a2,a3,den;
  {
    unsigned u = h2u[(unsigned)n*10u + cl];
    f32x2 f0 = __builtin_amdgcn_cvt_pk_f32_fp8((int)u, false);
    f32x2 f1 = __builtin_amdgcn_cvt_pk_f32_fp8((int)u, true);
    a0 = wself*f0[0]; a1 = wself*f0[1]; a2 = wself*f1[0]; a3 = wself*f1[1];
    den = wself;
  }
  if (rs < re){
    int last = re - 1;
    unsigned cs0 = (unsigned)csr[min(rs+0,last)];
    unsigned cs1 = (unsigned)csr[min(rs+1,last)];
    unsigned cs2 = (unsigned)csr[min(rs+2,last)];
    unsigned cs3 = (unsigned)csr[min(rs+3,last)];
    unsigned cs4 = (unsigned)csr[min(rs+4,last)];
    unsigned cs5 = (unsigned)csr[min(rs+5,last)];
    unsigned cs6 = (unsigned)csr[min(rs+6,last)];
    unsigned cs7 = (unsigned)csr[min(rs+7,last)];
    float aj0 = a2j[cs0], aj1 = a2j[cs1], aj2 = a2j[cs2], aj3 = a2j[cs3];
    float aj4 = a2j[cs4], aj5 = a2j[cs5], aj6 = a2j[cs6], aj7 = a2j[cs7];
    unsigned u0 = h2u[cs0*10u + cl];
    unsigned u1 = h2u[cs1*10u + cl];
    unsigned u2 = h2u[cs2*10u + cl];
    unsigned u3 = h2u[cs3*10u + cl];
    int e0 = rs;

#define AGG2_ST(US, CF, CS, AJ, OFF)                                         \
    {                                                                        \
      unsigned cur = US;                                                     \
      US = h2u[CF*10u + cl];                                                 \
      unsigned nc = (unsigned)csr[min(e0+OFF+8, last)];                      \
      float wg = (e0+OFF < re)? __expf(lrelu02(ai + AJ)) : 0.f;              \
      den += wg;                                                             \
      f32x2 g0 = __builtin_amdgcn_cvt_pk_f32_fp8((int)cur, false);           \
      f32x2 g1 = __builtin_amdgcn_cvt_pk_f32_fp8((int)cur, true);            \
      a0 += wg*g0[0]; a1 += wg*g0[1]; a2 += wg*g1[0]; a3 += wg*g1[1];        \
      CS = nc; AJ = a2j[nc];                                                 \
    }

    while (e0 < re){
      AGG2_ST(u0, cs4, cs0, aj0, 0)
      AGG2_ST(u1, cs5, cs1, aj1, 1)
      AGG2_ST(u2, cs6, cs2, aj2, 2)
      AGG2_ST(u3, cs7, cs3, aj3, 3)
      AGG2_ST(u0, cs0, cs4, aj4, 4)
      AGG2_ST(u1, cs1, cs5, aj5, 5)
      AGG2_ST(u2, cs2, cs6, aj6, 6)
      AGG2_ST(u3, cs3, cs7, aj7, 7)
      e0 += 8;
    }
#undef AGG2_ST
  }
  float invd = 1.f/(den + 1e-16f);
  const float4* b4 = (const float4*)(bias + 4*cl);
  float4 bb = b4[0];
  float v0 = a0*invd + bb.x, v1 = a1*invd + bb.y;
  float v2 = a2*invd + bb.z, v3 = a3*invd + bb.w;
  float mv = act ? fmaxf(fmaxf(v0,v1), fmaxf(v2,v3)) : -INFINITY;
  #pragma unroll
  for (int off = 1; off < 16; off <<= 1) mv = fmaxf(mv, __shfl_xor(mv, off));
  float se = act ? (__expf(v0-mv)+__expf(v1-mv)+__expf(v2-mv)+__expf(v3-mv)) : 0.f;
  #pragma unroll
  for (int off = 1; off < 16; off <<= 1) se += __shfl_xor(se, off);
  float ls = __logf(se);
  if (act){
    float4 o = make_float4(v0-mv-ls, v1-mv-ls, v2-mv-ls, v3-mv-ls);
    ((float4*)out)[(unsigned)n*10u + cl] = o;
  }
}

extern "C" void kernel_launch(void* const* d_in, const int* in_sizes, int n_in,
                              void* d_out, int out_size, void* d_ws, size_t ws_size,
                              hipStream_t stream){
  const float* x     = (const float*)d_in[0];
  const int*   ei    = (const int*)  d_in[1];
  const float* W1    = (const float*)d_in[2];
  const float* b1    = (const float*)d_in[3];
  const float* att1  = (const float*)d_in[4];
  const float* bias1 = (const float*)d_in[5];
  const float* W2    = (const float*)d_in[6];
  const float* b2    = (const float*)d_in[7];
  const float* att2  = (const float*)d_in[8];
  const float* bias2 = (const float*)d_in[9];
  int N = in_sizes[0] / 128;
  int E = in_sizes[1] / 2;
  const int* src = ei;
  const int* dst = ei + E;

  char* ws = (char*)d_ws;
  size_t off = 0;
  auto alloc = [&](size_t bytes)->char*{
    char* p = ws + off; off += (bytes + 255) & ~(size_t)255; return p;
  };
  unsigned char* h1f8 = (unsigned char*)alloc((size_t)N*128);   // fp8 row-major
  _Float16*      x2h  = (_Float16*)alloc((size_t)N*128*2);      // f16 (MFMA A)
  unsigned char* h2f8 = (unsigned char*)alloc((size_t)N*40);    // fp8 row-major
  float* a1i  = (float*)alloc((size_t)N*8*4);
  float* a1j  = (float*)alloc((size_t)N*8*4);
  float* a2i  = (float*)alloc((size_t)N*4);
  float* a2j  = (float*)alloc((size_t)N*4);
  _Float16* W1h   = (_Float16*)alloc(16384*2);
  _Float16* W2h   = (_Float16*)alloc(6144*2);
  _Float16* attB1 = (_Float16*)alloc(2048*2);
  _Float16* attB2 = (_Float16*)alloc(2048*2);
  float* consts = (float*)alloc(18*4);
  int*   rowst = (int*)  alloc((size_t)(N+1)*4);
  int*   csr   = (int*)  alloc((size_t)E*4);

  int nbucket = (N + BMASK) >> BSHIFT;               // 391 for N=100K (<=512)
  int nb1 = nbucket + 1;
  int nchunk = (E + SPLIT_CHUNK - 1)/SPLIT_CHUNK;    // 391 for E=1.6M (<=512)

  int*   hp     = (int*)alloc((size_t)nchunk*nb1*4); // per-(block,bucket) offsets
  int*   tot    = (int*)alloc((size_t)nbucket*4);
  int*   bstart = (int*)alloc((size_t)(nbucket+1)*4);
  int*   tmp    = (int*)x2h;                         // alias: dead until k_agg1 writes x2h

  int gblk = ((N+15)/16 + 3)/4;  // 4 waves/block, 16 nodes/wave (gemm1)

  k_prep<<<105, 256, 0, stream>>>(W1, b1, att1, W2, b2, att2, W1h, W2h, attB1, attB2, consts);
  k_fused1<<<nchunk + gblk, 256, 0, stream>>>(src, dst, hp, tmp, E, nb1, nchunk,
                                              x, W1h, attB1, b1, consts, h1f8, a1i, a1j, N);
  k_colsum<<<nbucket, 256, 0, stream>>>(hp, tot, nchunk, nb1);
  k_bscan<<<1, 256, 0, stream>>>(tot, bstart, rowst, nbucket, E, N);
  k_final<<<nbucket, 256, 0, stream>>>(tmp, hp, bstart, rowst, csr, nchunk, nb1, N);

  k_agg1<<<(N+3)/4, 256, 0, stream>>>((const uint2*)h1f8, a1i, a1j, rowst, csr, bias1,
                                      (uint4*)x2h, N);

  k_gemm2<<<gblk, 256, 0, stream>>>(x2h, W2h, attB2, b2, consts, h2f8, a2i, a2j, N);
  k_agg2<<<(N+15)/16, 256, 0, stream>>>((const unsigned*)h2f8, a2i, a2j, rowst, csr, bias2, (float*)d_out, N);
}

// Round 12
// 283.033 us; speedup vs baseline: 1.1251x; 1.1251x over previous
//
#include <hip/hip_runtime.h>
#include <hip/hip_fp16.h>
#include <math.h>

// 2-layer GAT. f16 MFMA GEMMs (fused attention-scalar B-tiles, fused fp32->f16
// A-convert), fp8-e4m3 feature storage for the edge gathers, single-pass
// segment softmax, fp32 accumulation.
//
// CSR build (R17, validated R6): ATOMIC-FREE multi-split; split fused with
// gemm1. Zero device atomics.
//
// Aggregation: R3 8-stage pipeline bodies (validated best: 63.9us, VGPR 28,
// 2.80 TB/s). FUSION LEDGER: R16 diet regressed; R19 barrier-coupled fusion
// = degree-tail 1.45x; R20 coupling-free fusion = VGPR-union occupancy
// collapse; R22 wave-per-segment gather = parallelism collapse (+27.6us,
// reverted -- the old consecutive-int serial loop was ALREADY line-efficient;
// check address arithmetic before bandwidth theories).
//
// R23: k_final gather = R7 structure (256 threads across segments) + 4-wide
// load->reg batching: old inner loop serialized load->waitcnt->LDS-write per
// int (~500cy/elem if L2-miss, compiler can't unroll past runtime cnt).
// Batching keeps 4 loads in flight per waitcnt -> ~4x fewer stall windows.
// Same parallelism, same traffic.

typedef _Float16 f16x8 __attribute__((ext_vector_type(8)));   // 8 f16 (4 VGPRs)
typedef float f32x4 __attribute__((ext_vector_type(4)));
typedef float f32x2 __attribute__((ext_vector_type(2)));

__device__ __forceinline__ float lrelu02(float x){ return x > 0.f ? x : 0.2f*x; }
__device__ __forceinline__ unsigned char f2fp8(float v){
  return (unsigned char)(__builtin_amdgcn_cvt_pk_fp8_f32(v, v, 0, false) & 0xff);
}

#define BSHIFT 8                 // 256 nodes per bucket
#define BMASK  255
#define SPLIT_CHUNK 4096         // edges per split block (= private tmp region)

// ---------------- split body: block-private bucket sort (NO device atomics) ----------------
__device__ __forceinline__ void split_body(int blk, const int* __restrict__ src,
    const int* __restrict__ dst, int* __restrict__ hp, int* __restrict__ tmp,
    int E, int nb1){
  __shared__ int hist[512];
  __shared__ int hoff[512];
  __shared__ int sb[256];
  int tid = threadIdx.x;
  #pragma unroll
  for (int t = tid; t < 512; t += 256) hist[t] = 0;
  __syncthreads();
  int lo = blk*SPLIT_CHUNK;
  int ds[16], ss[16];
  #pragma unroll
  for (int k = 0; k < 16; ++k){
    int i = lo + tid + k*256;
    bool p = i < E;
    ds[k] = p ? dst[i] : 0;
    ss[k] = p ? src[i] : 0;
    if (p) atomicAdd(&hist[ds[k] >> BSHIFT], 1);     // LDS atomic
  }
  __syncthreads();
  int v0 = hist[2*tid], v1 = hist[2*tid+1];
  sb[tid] = v0 + v1;
  __syncthreads();
  for (int off = 1; off < 256; off <<= 1){
    int x = (tid >= off) ? sb[tid-off] : 0;
    __syncthreads();
    sb[tid] += x;
    __syncthreads();
  }
  int base = (tid == 0) ? 0 : sb[tid-1];
  hoff[2*tid]   = base;
  hoff[2*tid+1] = base + v0;
  __syncthreads();
  for (int b = tid; b < nb1; b += 256) hp[blk*nb1 + b] = hoff[b];
  __syncthreads();
  #pragma unroll
  for (int k = 0; k < 16; ++k){
    int i = lo + tid + k*256;
    if (i < E){
      int r = atomicAdd(&hoff[ds[k] >> BSHIFT], 1);  // LDS atomic, private region pos
      tmp[blk*SPLIT_CHUNK + r] = ss[k] | ((ds[k] & BMASK) << 17);
    }
  }
}

// ---------------- GEMM1 body (MFMA f16): h1 (fp8) + a1i/a1j ----------------
__device__ __forceinline__ void gemm1_body(int gb, const float* __restrict__ x,
    const _Float16* __restrict__ Wh, const _Float16* __restrict__ attB,
    const float* __restrict__ b1, const float* __restrict__ consts,
    unsigned char* __restrict__ h1f8, float* __restrict__ a1i, float* __restrict__ a1j, int N){
  int wid  = (gb*256 + (int)threadIdx.x) >> 6;
  int lane = threadIdx.x & 63;
  int m0 = wid*16;
  if (m0 >= N) return;
  int col = lane & 15, quad = lane >> 4;
  const float* xr = x + (size_t)(m0+col)*128 + quad*8;
  f32x4 acc[9];
  #pragma unroll
  for (int t=0;t<9;t++){ acc[t][0]=0.f; acc[t][1]=0.f; acc[t][2]=0.f; acc[t][3]=0.f; }
  #pragma unroll
  for (int q=0;q<4;q++){
    float4 f0 = ((const float4*)(xr + q*32))[0];
    float4 f1 = ((const float4*)(xr + q*32))[1];
    f16x8 a;
    a[0]=(_Float16)f0.x; a[1]=(_Float16)f0.y; a[2]=(_Float16)f0.z; a[3]=(_Float16)f0.w;
    a[4]=(_Float16)f1.x; a[5]=(_Float16)f1.y; a[6]=(_Float16)f1.z; a[7]=(_Float16)f1.w;
    #pragma unroll
    for (int t=0;t<8;t++){
      const f16x8* Bp = (const f16x8*)(Wh + (size_t)(t*16+col)*128 + q*32 + quad*8);
      acc[t] = __builtin_amdgcn_mfma_f32_16x16x32_f16(a, *Bp, acc[t], 0,0,0);
    }
    const f16x8* Ap = (const f16x8*)(attB + (size_t)col*128 + q*32 + quad*8);
    acc[8] = __builtin_amdgcn_mfma_f32_16x16x32_f16(a, *Ap, acc[8], 0,0,0);
  }
  #pragma unroll
  for (int t=0;t<8;t++){
    int c = t*16 + col;
    float bb = b1[c];
    #pragma unroll
    for (int r=0;r<4;r++){
      h1f8[(size_t)(m0 + quad*4 + r)*128 + c] = f2fp8(acc[t][r] + bb);
    }
  }
  float hb = consts[col];
  #pragma unroll
  for (int r=0;r<4;r++){
    int node = m0 + quad*4 + r;
    float v = acc[8][r] + hb;
    if (col < 8) a1i[node*8 + col] = v;
    else         a1j[node*8 + (col-8)] = v;
  }
}

// ---------------- fused: split (independent) || gemm1 ----------------
__global__ __launch_bounds__(256) void k_fused1(const int* __restrict__ src,
    const int* __restrict__ dst, int* __restrict__ hp, int* __restrict__ tmp,
    int E, int nb1, int nchunk,
    const float* __restrict__ x, const _Float16* __restrict__ Wh,
    const _Float16* __restrict__ attB, const float* __restrict__ b1,
    const float* __restrict__ consts, unsigned char* __restrict__ h1f8,
    float* __restrict__ a1i, float* __restrict__ a1j, int N){
  if ((int)blockIdx.x < nchunk)
    split_body(blockIdx.x, src, dst, hp, tmp, E, nb1);
  else
    gemm1_body(blockIdx.x - nchunk, x, Wh, attB, b1, consts, h1f8, a1i, a1j, N);
}

// ---------------- column sums: tot[b] = sum_blk cnt[blk][b] ----------------
__global__ __launch_bounds__(256) void k_colsum(const int* __restrict__ hp,
    int* __restrict__ tot, int nchunk, int nb1){
  __shared__ int red[256];
  int b = blockIdx.x;
  int t = threadIdx.x;
  int s = 0;
  for (int blk = t; blk < nchunk; blk += 256)
    s += hp[blk*nb1 + b + 1] - hp[blk*nb1 + b];
  red[t] = s;
  __syncthreads();
  for (int off = 128; off > 0; off >>= 1){
    if (t < off) red[t] += red[t+off];
    __syncthreads();
  }
  if (t == 0) tot[b] = red[0];
}

// ---------------- bucket scan: tot -> bstart (exclusive) ----------------
__global__ void k_bscan(const int* __restrict__ tot, int* __restrict__ bstart,
                        int* __restrict__ rowstart, int nbucket, int E, int N){
  __shared__ int lds[256];
  int t = threadIdx.x;
  int v[4]; int s = 0;
  #pragma unroll
  for (int k = 0; k < 4; ++k){
    int idx = t*4 + k;
    v[k] = (idx < nbucket) ? tot[idx] : 0;
    s += v[k];
  }
  lds[t] = s;
  __syncthreads();
  for (int off = 1; off < 256; off <<= 1){
    int x = (t >= off) ? lds[t-off] : 0;
    __syncthreads();
    lds[t] += x;
    __syncthreads();
  }
  int run = (t == 0) ? 0 : lds[t-1];
  #pragma unroll
  for (int k = 0; k < 4; ++k){
    int idx = t*4 + k;
    if (idx < nbucket) bstart[idx] = run;
    run += v[k];
  }
  if (t == 0){ bstart[nbucket] = E; rowstart[N] = E; }
}

// ---------------- finalize: gather per-block segments -> node sort -> csr ----------------
#define STAGE_CAP 6144   // bucket mean 4096, sd ~64 -> mean+32sd headroom
__global__ __launch_bounds__(256) void k_final(const int* __restrict__ tmp,
    const int* __restrict__ hp, const int* __restrict__ bstart,
    int* __restrict__ rowstart, int* __restrict__ csr, int nchunk, int nb1, int N){
  __shared__ int stage[STAGE_CAP];
  __shared__ int c0[512];
  __shared__ int cv[512];
  __shared__ int ce[512];
  __shared__ int sb[256];
  __shared__ int h[256];
  __shared__ int sc[256];
  __shared__ int cur[256];
  int b = blockIdx.x;
  int tid = threadIdx.x;
  int base = bstart[b];
  int tot  = bstart[b+1] - base;
  #pragma unroll
  for (int t = tid; t < 512; t += 256){ c0[t] = 0; cv[t] = 0; }
  __syncthreads();
  for (int blk = tid; blk < nchunk; blk += 256){
    int o0 = hp[blk*nb1 + b];
    int o1 = hp[blk*nb1 + b + 1];
    c0[blk] = o0;
    cv[blk] = o1 - o0;
  }
  __syncthreads();
  int v0 = cv[2*tid], v1 = cv[2*tid+1];
  sb[tid] = v0 + v1;
  __syncthreads();
  for (int off = 1; off < 256; off <<= 1){
    int x = (tid >= off) ? sb[tid-off] : 0;
    __syncthreads();
    sb[tid] += x;
    __syncthreads();
  }
  int pbase = (tid == 0) ? 0 : sb[tid-1];
  ce[2*tid]   = pbase;
  ce[2*tid+1] = pbase + v0;
  __syncthreads();
  // gather segments into LDS stage: R7 structure (256 threads across
  // segments, consecutive-int reads = line-efficient) + 4-wide load->reg
  // batching so 4 loads stay in flight per waitcnt (R23).
  for (int blk = tid; blk < nchunk; blk += 256){
    int cnt = cv[blk];
    int out = ce[blk];
    const int* tb = tmp + blk*SPLIT_CHUNK + c0[blk];
    int j = 0;
    for (; j + 4 <= cnt; j += 4){
      int r0 = tb[j], r1 = tb[j+1], r2 = tb[j+2], r3 = tb[j+3];
      int o = out + j;
      if (o + 3 < STAGE_CAP){
        stage[o] = r0; stage[o+1] = r1; stage[o+2] = r2; stage[o+3] = r3;
      } else {
        if (o   < STAGE_CAP) stage[o]   = r0;
        if (o+1 < STAGE_CAP) stage[o+1] = r1;
        if (o+2 < STAGE_CAP) stage[o+2] = r2;
        if (o+3 < STAGE_CAP) stage[o+3] = r3;
      }
    }
    for (; j < cnt; ++j){
      int o = out + j;
      if (o < STAGE_CAP) stage[o] = tb[j];
    }
  }
  if (tid < 256) h[tid] = 0;
  __syncthreads();
  if (tot > STAGE_CAP) tot = STAGE_CAP;
  for (int i = tid; i < tot; i += 256) atomicAdd(&h[stage[i] >> 17], 1);
  __syncthreads();
  sc[tid] = h[tid];
  __syncthreads();
  for (int off = 1; off < 256; off <<= 1){
    int x = (tid >= off) ? sc[tid-off] : 0;
    __syncthreads();
    sc[tid] += x;
    __syncthreads();
  }
  {
    int excl = sc[tid] - h[tid];
    int node = b*256 + tid;
    if (node < N) rowstart[node] = base + excl;
    cur[tid] = excl;
  }
  __syncthreads();
  for (int i = tid; i < tot; i += 256){
    int v = stage[i];
    int p = atomicAdd(&cur[v >> 17], 1);
    csr[base + p] = v & 0x1FFFF;
  }
}

// ---------------- weight prep: f16 weights + att-folded tiles + bias consts ----------------
__global__ void k_prep(const float* __restrict__ W1, const float* __restrict__ b1,
                       const float* __restrict__ att1,
                       const float* __restrict__ W2, const float* __restrict__ b2,
                       const float* __restrict__ att2,
                       _Float16* __restrict__ W1h, _Float16* __restrict__ W2h,
                       _Float16* __restrict__ attB1, _Float16* __restrict__ attB2,
                       float* __restrict__ consts){
  int i = blockIdx.x*blockDim.x + threadIdx.x;
  if (i < 16384){ W1h[i] = (_Float16)W1[i]; return; }
  i -= 16384;
  if (i < 6144){ int r = i >> 7; W2h[i] = (r < 40)? (_Float16)W2[i] : (_Float16)0.f; return; }
  i -= 6144;
  if (i < 2048){
    int j = i >> 7, k = i & 127;
    int h = j & 7, half = (j >> 3)*16;
    float s = 0.f;
    for (int c = 0; c < 16; ++c) s += att1[h*32 + half + c]*W1[(h*16+c)*128 + k];
    attB1[i] = (_Float16)s; return;
  }
  i -= 2048;
  if (i < 2048){
    int j = i >> 7, k = i & 127;
    float s = 0.f;
    if (j < 2){ const float* av = att2 + j*40; for (int c = 0; c < 40; ++c) s += av[c]*W2[c*128 + k]; }
    attB2[i] = (_Float16)s; return;
  }
  i -= 2048;
  if (i < 18){
    float s = 0.f;
    if (i < 8){ for (int c = 0; c < 16; ++c) s += b1[i*16+c]*att1[i*32+c]; }
    else if (i < 16){ int h = i-8; for (int c = 0; c < 16; ++c) s += b1[h*16+c]*att1[h*32+16+c]; }
    else if (i == 16){ for (int c = 0; c < 40; ++c) s += b2[c]*att2[c]; }
    else { for (int c = 0; c < 40; ++c) s += b2[c]*att2[40+c]; }
    consts[i] = s;
  }
}

// ---------------- layer-1 agg body (EXACT R3, 63.9us validated) ----------------
__device__ __forceinline__ void agg1_node(int n, const uint2* __restrict__ h1q,
    const float* __restrict__ a1i, const float* __restrict__ a1j,
    const int* __restrict__ rowstart, const int* __restrict__ csr,
    const float* __restrict__ bias, uint4* __restrict__ x2u4, int N){
  if (n >= N) return;
  int lane = threadIdx.x & 63;
  int ql = lane & 15, qt = lane >> 4;
  unsigned hd = (unsigned)ql >> 1;
  int rs = rowstart[n], re = rowstart[n+1];
  float ai2 = a1i[(unsigned)n*8u + hd];
  float a0=0.f,a1=0.f,a2=0.f,a3=0.f,a4=0.f,a5=0.f,a6=0.f,a7=0.f,den=0.f;
  {
    float w = (qt==0)? __expf(lrelu02(ai2 + a1j[(unsigned)n*8u + hd])) : 0.f;
    uint2 u = h1q[(unsigned)n*16u + (unsigned)ql];
    f32x2 f0 = __builtin_amdgcn_cvt_pk_f32_fp8((int)u.x, false);
    f32x2 f1 = __builtin_amdgcn_cvt_pk_f32_fp8((int)u.x, true);
    f32x2 f2 = __builtin_amdgcn_cvt_pk_f32_fp8((int)u.y, false);
    f32x2 f3 = __builtin_amdgcn_cvt_pk_f32_fp8((int)u.y, true);
    a0=w*f0[0]; a1=w*f0[1]; a2=w*f1[0]; a3=w*f1[1];
    a4=w*f2[0]; a5=w*f2[1]; a6=w*f3[0]; a7=w*f3[1];
    den = w;
  }
  int last = re - 1;
  if (rs < re){
    unsigned cs0 = (unsigned)csr[min(rs+ 0+qt,last)];
    unsigned cs1 = (unsigned)csr[min(rs+ 4+qt,last)];
    unsigned cs2 = (unsigned)csr[min(rs+ 8+qt,last)];
    unsigned cs3 = (unsigned)csr[min(rs+12+qt,last)];
    unsigned cs4 = (unsigned)csr[min(rs+16+qt,last)];
    unsigned cs5 = (unsigned)csr[min(rs+20+qt,last)];
    unsigned cs6 = (unsigned)csr[min(rs+24+qt,last)];
    unsigned cs7 = (unsigned)csr[min(rs+28+qt,last)];
    float aj0 = a1j[cs0*8u+hd], aj1 = a1j[cs1*8u+hd];
    float aj2 = a1j[cs2*8u+hd], aj3 = a1j[cs3*8u+hd];
    float aj4 = a1j[cs4*8u+hd], aj5 = a1j[cs5*8u+hd];
    float aj6 = a1j[cs6*8u+hd], aj7 = a1j[cs7*8u+hd];
    uint2 u0 = h1q[(size_t)cs0*16u + (unsigned)ql];
    uint2 u1 = h1q[(size_t)cs1*16u + (unsigned)ql];
    uint2 u2 = h1q[(size_t)cs2*16u + (unsigned)ql];
    uint2 u3 = h1q[(size_t)cs3*16u + (unsigned)ql];
    int e0 = rs;

#define AGG1_ST(US, CF, CS, AJ, OFF)                                         \
    {                                                                        \
      uint2 cur = US;                                                        \
      US = h1q[(size_t)CF*16u + (unsigned)ql];                               \
      unsigned nc = (unsigned)csr[min(e0+OFF+32+qt, last)];                  \
      float w = (e0+OFF+qt < re)? __expf(lrelu02(ai2 + AJ)) : 0.f;           \
      den += w;                                                              \
      f32x2 g0 = __builtin_amdgcn_cvt_pk_f32_fp8((int)cur.x, false);         \
      f32x2 g1 = __builtin_amdgcn_cvt_pk_f32_fp8((int)cur.x, true);          \
      f32x2 g2 = __builtin_amdgcn_cvt_pk_f32_fp8((int)cur.y, false);         \
      f32x2 g3 = __builtin_amdgcn_cvt_pk_f32_fp8((int)cur.y, true);          \
      a0 += w*g0[0]; a1 += w*g0[1]; a2 += w*g1[0]; a3 += w*g1[1];            \
      a4 += w*g2[0]; a5 += w*g2[1]; a6 += w*g3[0]; a7 += w*g3[1];            \
      CS = nc; AJ = a1j[nc*8u + hd];                                         \
    }

    while (e0 < re){
      AGG1_ST(u0, cs4, cs0, aj0, 0)
      if (e0+4 >= re) break;
      AGG1_ST(u1, cs5, cs1, aj1, 4)
      if (e0+8 >= re) break;
      AGG1_ST(u2, cs6, cs2, aj2, 8)
      if (e0+12 >= re) break;
      AGG1_ST(u3, cs7, cs3, aj3, 12)
      if (e0+16 >= re) break;
      AGG1_ST(u0, cs0, cs4, aj4, 16)
      if (e0+20 >= re) break;
      AGG1_ST(u1, cs1, cs5, aj5, 20)
      if (e0+24 >= re) break;
      AGG1_ST(u2, cs2, cs6, aj6, 24)
      if (e0+28 >= re) break;
      AGG1_ST(u3, cs3, cs7, aj7, 28)
      e0 += 32;
    }
#undef AGG1_ST
  }
  #pragma unroll
  for (int off = 16; off < 64; off <<= 1){
    den += __shfl_xor(den, off);
    a0 += __shfl_xor(a0, off); a1 += __shfl_xor(a1, off);
    a2 += __shfl_xor(a2, off); a3 += __shfl_xor(a3, off);
    a4 += __shfl_xor(a4, off); a5 += __shfl_xor(a5, off);
    a6 += __shfl_xor(a6, off); a7 += __shfl_xor(a7, off);
  }
  if (qt == 0){
    float invd = 1.f/(den + 1e-16f);
    const float4* b4 = (const float4*)(bias + 8*ql);
    float4 bl = b4[0], bh = b4[1];
    float o0=a0*invd+bl.x, o1=a1*invd+bl.y, o2=a2*invd+bl.z, o3=a3*invd+bl.w;
    float o4=a4*invd+bh.x, o5=a5*invd+bh.y, o6=a6*invd+bh.z, o7=a7*invd+bh.w;
    o0=(o0>0.f)?o0:(__expf(o0)-1.f); o1=(o1>0.f)?o1:(__expf(o1)-1.f);
    o2=(o2>0.f)?o2:(__expf(o2)-1.f); o3=(o3>0.f)?o3:(__expf(o3)-1.f);
    o4=(o4>0.f)?o4:(__expf(o4)-1.f); o5=(o5>0.f)?o5:(__expf(o5)-1.f);
    o6=(o6>0.f)?o6:(__expf(o6)-1.f); o7=(o7>0.f)?o7:(__expf(o7)-1.f);
    __half2 p0 = __floats2half2_rn(o0,o1), p1 = __floats2half2_rn(o2,o3);
    __half2 p2 = __floats2half2_rn(o4,o5), p3 = __floats2half2_rn(o6,o7);
    uint4 o;
    o.x = *(unsigned*)&p0; o.y = *(unsigned*)&p1; o.z = *(unsigned*)&p2; o.w = *(unsigned*)&p3;
    x2u4[(unsigned)n*16u + (unsigned)ql] = o;
  }
}

// ---------------- agg1: one wave per node ----------------
__global__ __launch_bounds__(256) void k_agg1(const uint2* __restrict__ h1q,
    const float* __restrict__ a1i, const float* __restrict__ a1j,
    const int* __restrict__ rowstart, const int* __restrict__ csr,
    const float* __restrict__ bias, uint4* __restrict__ x2u4, int N){
  int n = (blockIdx.x*256 + (int)threadIdx.x) >> 6;
  agg1_node(n, h1q, a1i, a1j, rowstart, csr, bias, x2u4, N);
}

// ---------------- GEMM2 (MFMA f16): h2 (fp8) + a2i/a2j ----------------
__global__ __launch_bounds__(256) void k_gemm2(const _Float16* __restrict__ xh,
    const _Float16* __restrict__ Wh, const _Float16* __restrict__ attB,
    const float* __restrict__ b2, const float* __restrict__ consts,
    unsigned char* __restrict__ h2f8, float* __restrict__ a2i, float* __restrict__ a2j, int N){
  int wid  = (blockIdx.x*256 + threadIdx.x) >> 6;
  int lane = threadIdx.x & 63;
  int m0 = wid*16;
  if (m0 >= N) return;
  int col = lane & 15, quad = lane >> 4;
  const f16x8* A8 = (const f16x8*)(xh + (size_t)(m0+col)*128 + quad*8);
  f32x4 acc[4];
  #pragma unroll
  for (int t=0;t<4;t++){ acc[t][0]=0.f; acc[t][1]=0.f; acc[t][2]=0.f; acc[t][3]=0.f; }
  #pragma unroll
  for (int q=0;q<4;q++){
    f16x8 a = A8[q*4];
    #pragma unroll
    for (int t=0;t<3;t++){
      const f16x8* Bp = (const f16x8*)(Wh + (size_t)(t*16+col)*128 + q*32 + quad*8);
      acc[t] = __builtin_amdgcn_mfma_f32_16x16x32_f16(a, *Bp, acc[t], 0,0,0);
    }
    const f16x8* Bp2 = (const f16x8*)(attB + (size_t)col*128 + q*32 + quad*8);
    acc[3] = __builtin_amdgcn_mfma_f32_16x16x32_f16(a, *Bp2, acc[3], 0,0,0);
  }
  #pragma unroll
  for (int t=0;t<3;t++){
    int c = t*16 + col;
    if (c < 40){
      float bb = b2[c];
      #pragma unroll
      for (int r=0;r<4;r++){
        h2f8[(size_t)(m0 + quad*4 + r)*40 + c] = f2fp8(acc[t][r] + bb);
      }
    }
  }
  if (col < 2){
    float cc = consts[16 + col];
    #pragma unroll
    for (int r=0;r<4;r++){
      int node = m0 + quad*4 + r;
      if (col == 0) a2i[node] = acc[3][r] + cc;
      else          a2j[node] = acc[3][r] + cc;
    }
  }
}

// ---------------- layer-2 fused softmax+aggregate + log_softmax (EXACT R3) ----------------
__global__ __launch_bounds__(256) void k_agg2(const unsigned* __restrict__ h2u,
    const float* __restrict__ a2i, const float* __restrict__ a2j,
    const int* __restrict__ rowstart, const int* __restrict__ csr,
    const float* __restrict__ bias, float* __restrict__ out, int N){
  int lane = threadIdx.x & 63;
  int wid = (blockIdx.x*blockDim.x + threadIdx.x) >> 6;
  int qt = lane >> 4, ql = lane & 15;
  int n = wid*4 + qt;
  if (n >= N) return;
  bool act = ql < 10;
  unsigned cl = act ? (unsigned)ql : 0u;
  int rs = rowstart[n], re = rowstart[n+1];
  float ai = a2i[n];
  float wself = __expf(lrelu02(ai + a2j[n]));
  float a0,a1,a2,a3,den;
  {
    unsigned u = h2u[(unsigned)n*10u + cl];
    f32x2 f0 = __builtin_amdgcn_cvt_pk_f32_fp8((int)u, false);
    f32x2 f1 = __builtin_amdgcn_cvt_pk_f32_fp8((int)u, true);
    a0 = wself*f0[0]; a1 = wself*f0[1]; a2 = wself*f1[0]; a3 = wself*f1[1];
    den = wself;
  }
  if (rs < re){
    int last = re - 1;
    unsigned cs0 = (unsigned)csr[min(rs+0,last)];
    unsigned cs1 = (unsigned)csr[min(rs+1,last)];
    unsigned cs2 = (unsigned)csr[min(rs+2,last)];
    unsigned cs3 = (unsigned)csr[min(rs+3,last)];
    unsigned cs4 = (unsigned)csr[min(rs+4,last)];
    unsigned cs5 = (unsigned)csr[min(rs+5,last)];
    unsigned cs6 = (unsigned)csr[min(rs+6,last)];
    unsigned cs7 = (unsigned)csr[min(rs+7,last)];
    float aj0 = a2j[cs0], aj1 = a2j[cs1], aj2 = a2j[cs2], aj3 = a2j[cs3];
    float aj4 = a2j[cs4], aj5 = a2j[cs5], aj6 = a2j[cs6], aj7 = a2j[cs7];
    unsigned u0 = h2u[cs0*10u + cl];
    unsigned u1 = h2u[cs1*10u + cl];
    unsigned u2 = h2u[cs2*10u + cl];
    unsigned u3 = h2u[cs3*10u + cl];
    int e0 = rs;

#define AGG2_ST(US, CF, CS, AJ, OFF)                                         \
    {                                                                        \
      unsigned cur = US;                                                     \
      US = h2u[CF*10u + cl];                                                 \
      unsigned nc = (unsigned)csr[min(e0+OFF+8, last)];                      \
      float wg = (e0+OFF < re)? __expf(lrelu02(ai + AJ)) : 0.f;              \
      den += wg;                                                             \
      f32x2 g0 = __builtin_amdgcn_cvt_pk_f32_fp8((int)cur, false);           \
      f32x2 g1 = __builtin_amdgcn_cvt_pk_f32_fp8((int)cur, true);            \
      a0 += wg*g0[0]; a1 += wg*g0[1]; a2 += wg*g1[0]; a3 += wg*g1[1];        \
      CS = nc; AJ = a2j[nc];                                                 \
    }

    while (e0 < re){
      AGG2_ST(u0, cs4, cs0, aj0, 0)
      AGG2_ST(u1, cs5, cs1, aj1, 1)
      AGG2_ST(u2, cs6, cs2, aj2, 2)
      AGG2_ST(u3, cs7, cs3, aj3, 3)
      AGG2_ST(u0, cs0, cs4, aj4, 4)
      AGG2_ST(u1, cs1, cs5, aj5, 5)
      AGG2_ST(u2, cs2, cs6, aj6, 6)
      AGG2_ST(u3, cs3, cs7, aj7, 7)
      e0 += 8;
    }
#undef AGG2_ST
  }
  float invd = 1.f/(den + 1e-16f);
  const float4* b4 = (const float4*)(bias + 4*cl);
  float4 bb = b4[0];
  float v0 = a0*invd + bb.x, v1 = a1*invd + bb.y;
  float v2 = a2*invd + bb.z, v3 = a3*invd + bb.w;
  float mv = act ? fmaxf(fmaxf(v0,v1), fmaxf(v2,v3)) : -INFINITY;
  #pragma unroll
  for (int off = 1; off < 16; off <<= 1) mv = fmaxf(mv, __shfl_xor(mv, off));
  float se = act ? (__expf(v0-mv)+__expf(v1-mv)+__expf(v2-mv)+__expf(v3-mv)) : 0.f;
  #pragma unroll
  for (int off = 1; off < 16; off <<= 1) se += __shfl_xor(se, off);
  float ls = __logf(se);
  if (act){
    float4 o = make_float4(v0-mv-ls, v1-mv-ls, v2-mv-ls, v3-mv-ls);
    ((float4*)out)[(unsigned)n*10u + cl] = o;
  }
}

extern "C" void kernel_launch(void* const* d_in, const int* in_sizes, int n_in,
                              void* d_out, int out_size, void* d_ws, size_t ws_size,
                              hipStream_t stream){
  const float* x     = (const float*)d_in[0];
  const int*   ei    = (const int*)  d_in[1];
  const float* W1    = (const float*)d_in[2];
  const float* b1    = (const float*)d_in[3];
  const float* att1  = (const float*)d_in[4];
  const float* bias1 = (const float*)d_in[5];
  const float* W2    = (const float*)d_in[6];
  const float* b2    = (const float*)d_in[7];
  const float* att2  = (const float*)d_in[8];
  const float* bias2 = (const float*)d_in[9];
  int N = in_sizes[0] / 128;
  int E = in_sizes[1] / 2;
  const int* src = ei;
  const int* dst = ei + E;

  char* ws = (char*)d_ws;
  size_t off = 0;
  auto alloc = [&](size_t bytes)->char*{
    char* p = ws + off; off += (bytes + 255) & ~(size_t)255; return p;
  };
  unsigned char* h1f8 = (unsigned char*)alloc((size_t)N*128);   // fp8 row-major
  _Float16*      x2h  = (_Float16*)alloc((size_t)N*128*2);      // f16 (MFMA A)
  unsigned char* h2f8 = (unsigned char*)alloc((size_t)N*40);    // fp8 row-major
  float* a1i  = (float*)alloc((size_t)N*8*4);
  float* a1j  = (float*)alloc((size_t)N*8*4);
  float* a2i  = (float*)alloc((size_t)N*4);
  float* a2j  = (float*)alloc((size_t)N*4);
  _Float16* W1h   = (_Float16*)alloc(16384*2);
  _Float16* W2h   = (_Float16*)alloc(6144*2);
  _Float16* attB1 = (_Float16*)alloc(2048*2);
  _Float16* attB2 = (_Float16*)alloc(2048*2);
  float* consts = (float*)alloc(18*4);
  int*   rowst = (int*)  alloc((size_t)(N+1)*4);
  int*   csr   = (int*)  alloc((size_t)E*4);

  int nbucket = (N + BMASK) >> BSHIFT;               // 391 for N=100K (<=512)
  int nb1 = nbucket + 1;
  int nchunk = (E + SPLIT_CHUNK - 1)/SPLIT_CHUNK;    // 391 for E=1.6M (<=512)

  int*   hp     = (int*)alloc((size_t)nchunk*nb1*4); // per-(block,bucket) offsets
  int*   tot    = (int*)alloc((size_t)nbucket*4);
  int*   bstart = (int*)alloc((size_t)(nbucket+1)*4);
  int*   tmp    = (int*)x2h;                         // alias: dead until k_agg1 writes x2h

  int gblk = ((N+15)/16 + 3)/4;  // 4 waves/block, 16 nodes/wave (gemm1)

  k_prep<<<105, 256, 0, stream>>>(W1, b1, att1, W2, b2, att2, W1h, W2h, attB1, attB2, consts);
  k_fused1<<<nchunk + gblk, 256, 0, stream>>>(src, dst, hp, tmp, E, nb1, nchunk,
                                              x, W1h, attB1, b1, consts, h1f8, a1i, a1j, N);
  k_colsum<<<nbucket, 256, 0, stream>>>(hp, tot, nchunk, nb1);
  k_bscan<<<1, 256, 0, stream>>>(tot, bstart, rowst, nbucket, E, N);
  k_final<<<nbucket, 256, 0, stream>>>(tmp, hp, bstart, rowst, csr, nchunk, nb1, N);

  k_agg1<<<(N+3)/4, 256, 0, stream>>>((const uint2*)h1f8, a1i, a1j, rowst, csr, bias1,
                                      (uint4*)x2h, N);

  k_gemm2<<<gblk, 256, 0, stream>>>(x2h, W2h, attB2, b2, consts, h2f8, a2i, a2j, N);
  k_agg2<<<(N+15)/16, 256, 0, stream>>>((const unsigned*)h2f8, a2i, a2j, rowst, csr, bias2, (float*)d_out, N);
}